// Round 1
// baseline (1508.989 us; speedup 1.0000x reference)
//
#include <hip/hip_runtime.h>
#include <math.h>

// Problem constants (from reference): N=50000, E=800000, IN=128, H=4, C=64, HC=256
#define HEADS 4
#define CH 64
#define HC 256

__device__ __forceinline__ float leaky02(float x) { return x > 0.f ? x : 0.2f * x; }

// ---------------------------------------------------------------------------
// Dual GEMM: h = x@W   (cols 0..255, block.x tiles 0..3)
//            skip = x@SW + Sb (block.x tiles 4..7)
// x: [Nn, K] row-major, W/SW: [K, 256] row-major.
// 64x64 tile, BK=16, 256 threads, 4x4 accum per thread. fp32.
// ---------------------------------------------------------------------------
__global__ __launch_bounds__(256) void gemm_dual(
    const float* __restrict__ x, const float* __restrict__ W,
    const float* __restrict__ SW, const float* __restrict__ Sb,
    float* __restrict__ h, float* __restrict__ skip, int Nn, int K) {
  __shared__ float As[16][68];  // [k][row], row stride 68 floats (272B, 16B aligned)
  __shared__ float Bs[16][68];  // [k][col]

  const int t = threadIdx.x;
  const int colTile = blockIdx.x;        // 0..7
  const int rowBase = blockIdx.y * 64;
  const bool isW = colTile < 4;
  const float* __restrict__ B = isW ? W : SW;
  const int colBase = (isW ? colTile : colTile - 4) * 64;  // within [0,256)

  const int arow = t >> 2;          // 0..63
  const int akq  = (t & 3) * 4;     // 0,4,8,12
  const int tx = t & 15, ty = t >> 4;

  float acc[4][4] = {};

  for (int k0 = 0; k0 < K; k0 += 16) {
    // Load A tile: 64 rows x 16 k
    float4 av = make_float4(0.f, 0.f, 0.f, 0.f);
    int gr = rowBase + arow;
    if (gr < Nn) av = *reinterpret_cast<const float4*>(x + (size_t)gr * K + k0 + akq);
    As[akq + 0][arow] = av.x;
    As[akq + 1][arow] = av.y;
    As[akq + 2][arow] = av.z;
    As[akq + 3][arow] = av.w;
    // Load B tile: 16 k-rows x 64 cols
    float4 bv = *reinterpret_cast<const float4*>(B + (size_t)(k0 + ty) * HC + colBase + tx * 4);
    *reinterpret_cast<float4*>(&Bs[ty][tx * 4]) = bv;
    __syncthreads();

#pragma unroll
    for (int kk = 0; kk < 16; kk++) {
      float4 a = *reinterpret_cast<const float4*>(&As[kk][ty * 4]);
      float4 b = *reinterpret_cast<const float4*>(&Bs[kk][tx * 4]);
      acc[0][0] += a.x * b.x; acc[0][1] += a.x * b.y; acc[0][2] += a.x * b.z; acc[0][3] += a.x * b.w;
      acc[1][0] += a.y * b.x; acc[1][1] += a.y * b.y; acc[1][2] += a.y * b.z; acc[1][3] += a.y * b.w;
      acc[2][0] += a.z * b.x; acc[2][1] += a.z * b.y; acc[2][2] += a.z * b.z; acc[2][3] += a.z * b.w;
      acc[3][0] += a.w * b.x; acc[3][1] += a.w * b.y; acc[3][2] += a.w * b.z; acc[3][3] += a.w * b.w;
    }
    __syncthreads();
  }

#pragma unroll
  for (int i = 0; i < 4; i++) {
    int gr = rowBase + ty * 4 + i;
    if (gr >= Nn) continue;
#pragma unroll
    for (int j = 0; j < 4; j++) {
      int col = colBase + tx * 4 + j;
      float v = acc[i][j];
      if (isW) {
        h[(size_t)gr * HC + col] = v;
      } else {
        skip[(size_t)gr * HC + col] = v + Sb[col];
      }
    }
  }
}

// ---------------------------------------------------------------------------
// Attention logits: s[n,h] = sum_c h[n,h,c]*a_src[h,c], same for d.
// One block per node, wave per head, lane = channel.
// ---------------------------------------------------------------------------
__global__ __launch_bounds__(256) void sd_kernel(
    const float* __restrict__ h, const float* __restrict__ a_src,
    const float* __restrict__ a_dst, float* __restrict__ s, float* __restrict__ d,
    int Nn) {
  int n = blockIdx.x;
  int t = threadIdx.x;
  int head = t >> 6, lane = t & 63;
  float hv = h[(size_t)n * HC + t];
  float ps = hv * a_src[t];
  float pd = hv * a_dst[t];
#pragma unroll
  for (int off = 32; off >= 1; off >>= 1) {
    ps += __shfl_down(ps, off, 64);
    pd += __shfl_down(pd, off, 64);
  }
  if (lane == 0) {
    s[n * HEADS + head] = ps;
    d[n * HEADS + head] = pd;
  }
}

// ---------------------------------------------------------------------------
// CSR build: histogram of dst, exclusive scan, scatter src into CSR order.
// ---------------------------------------------------------------------------
__global__ void hist_kernel(const int* __restrict__ ei, int* __restrict__ counts, int E) {
  int e = blockIdx.x * 256 + threadIdx.x;
  if (e < E) atomicAdd(&counts[ei[E + e]], 1);
}

__global__ __launch_bounds__(1024) void scan_kernel(
    const int* __restrict__ counts, int* __restrict__ offsets,
    int* __restrict__ cursor, int n) {
  __shared__ int sdata[1024];
  __shared__ int srun;
  int tid = threadIdx.x;
  if (tid == 0) srun = 0;
  __syncthreads();
  for (int base = 0; base < n; base += 1024) {
    int i = base + tid;
    int v = (i < n) ? counts[i] : 0;
    sdata[tid] = v;
    __syncthreads();
    for (int off = 1; off < 1024; off <<= 1) {
      int tv = (tid >= off) ? sdata[tid - off] : 0;
      __syncthreads();
      sdata[tid] += tv;
      __syncthreads();
    }
    int run = srun;
    int excl = run + sdata[tid] - v;
    if (i < n) {
      offsets[i] = excl;
      cursor[i] = excl;
    }
    __syncthreads();
    if (tid == 1023) srun = run + sdata[1023];
    __syncthreads();
  }
  if (tid == 0) offsets[n] = srun;
}

__global__ void scatter_kernel(const int* __restrict__ ei, int* __restrict__ cursor,
                               int* __restrict__ csr, int E) {
  int e = blockIdx.x * 256 + threadIdx.x;
  if (e < E) {
    int dn = ei[E + e];
    int pos = atomicAdd(&cursor[dn], 1);
    csr[pos] = ei[e];
  }
}

// ---------------------------------------------------------------------------
// Aggregation + epilogue. One block per dst node, wave per head, lane = channel.
// Self-loop (src=dst=n) handled explicitly (reference appends loop edges).
// out[n,:] = elu( segsum(exp(e-m)*h[src]) / (denom+1e-16) + b + skip[n,:] )
// ---------------------------------------------------------------------------
__global__ __launch_bounds__(256) void agg_kernel(
    const float* __restrict__ h, const float* __restrict__ s,
    const float* __restrict__ d, const int* __restrict__ offsets,
    const int* __restrict__ csr, const float* __restrict__ b,
    const float* __restrict__ skip, float* __restrict__ xout, int Nn) {
  int n = blockIdx.x;
  int head = threadIdx.x >> 6;
  int lane = threadIdx.x & 63;
  int beg = offsets[n], end = offsets[n + 1];

  float dn = d[n * HEADS + head];
  float e_self = leaky02(s[n * HEADS + head] + dn);

  // Pass A: max over incoming edges (+ self loop)
  float m = e_self;
  for (int i = beg + lane; i < end; i += 64) {
    int sn = csr[i];
    m = fmaxf(m, leaky02(s[sn * HEADS + head] + dn));
  }
#pragma unroll
  for (int off = 32; off >= 1; off >>= 1) m = fmaxf(m, __shfl_xor(m, off, 64));

  // Pass B: accumulate exp(e-m) and exp(e-m)*h[src]
  float acc = 0.f, denom = 0.f;
  for (int base = beg; base < end; base += 64) {
    int cnt = min(64, end - base);
    int sn_l = 0;
    float e_l = 0.f;
    if (lane < cnt) {
      sn_l = csr[base + lane];
      e_l = __expf(leaky02(s[sn_l * HEADS + head] + dn) - m);
    }
    for (int j = 0; j < cnt; j++) {
      int sn = __shfl(sn_l, j, 64);
      float ex = __shfl(e_l, j, 64);
      denom += ex;
      acc += ex * h[(size_t)sn * HC + head * CH + lane];
    }
  }
  float exs = __expf(e_self - m);
  denom += exs;
  acc += exs * h[(size_t)n * HC + head * CH + lane];

  int col = head * CH + lane;
  float res = acc / (denom + 1e-16f) + b[col] + skip[(size_t)n * HC + col];
  xout[(size_t)n * HC + col] = res > 0.f ? res : expm1f(res);
}

// ---------------------------------------------------------------------------
extern "C" void kernel_launch(void* const* d_in, const int* in_sizes, int n_in,
                              void* d_out, int out_size, void* d_ws, size_t ws_size,
                              hipStream_t stream) {
  const float* x = (const float*)d_in[0];
  const int* ei = (const int*)d_in[1];
  const int Nn = in_sizes[0] / 128;   // 50000
  const int E = in_sizes[1] / 2;      // 800000

  // Per-layer params: W, a_src, a_dst, b, SW, Sb starting at index 2
  const float* W[3]; const float* asrc[3]; const float* adst[3];
  const float* bb[3]; const float* SW[3]; const float* Sb[3];
  for (int l = 0; l < 3; l++) {
    W[l]    = (const float*)d_in[2 + 6 * l + 0];
    asrc[l] = (const float*)d_in[2 + 6 * l + 1];
    adst[l] = (const float*)d_in[2 + 6 * l + 2];
    bb[l]   = (const float*)d_in[2 + 6 * l + 3];
    SW[l]   = (const float*)d_in[2 + 6 * l + 4];
    Sb[l]   = (const float*)d_in[2 + 6 * l + 5];
  }

  // Workspace layout (floats then ints)
  float* ws = (float*)d_ws;
  float* xbuf1 = ws;                       // N*256
  float* xbuf2 = xbuf1 + (size_t)Nn * HC;  // N*256
  float* hbuf  = xbuf2 + (size_t)Nn * HC;  // N*256
  float* skipb = hbuf + (size_t)Nn * HC;   // N*256
  float* sbuf  = skipb + (size_t)Nn * HC;  // N*4
  float* dbuf  = sbuf + (size_t)Nn * HEADS;
  int* counts  = (int*)(dbuf + (size_t)Nn * HEADS);  // N
  int* offsets = counts + Nn;                        // N+1
  int* cursor  = offsets + Nn + 1;                   // N
  int* csr     = cursor + Nn;                        // E

  // --- CSR build (dst is layer-invariant) ---
  hipMemsetAsync(counts, 0, (size_t)Nn * sizeof(int), stream);
  hist_kernel<<<(E + 255) / 256, 256, 0, stream>>>(ei, counts, E);
  scan_kernel<<<1, 1024, 0, stream>>>(counts, offsets, cursor, Nn);
  scatter_kernel<<<(E + 255) / 256, 256, 0, stream>>>(ei, cursor, csr, E);

  // --- Layers ---
  dim3 ggrid(8, (Nn + 63) / 64);
  const float* xin = x;
  float* xouts[3] = {xbuf1, xbuf2, (float*)d_out};
  for (int l = 0; l < 3; l++) {
    int K = (l == 0) ? 128 : 256;
    gemm_dual<<<ggrid, 256, 0, stream>>>(xin, W[l], SW[l], Sb[l], hbuf, skipb, Nn, K);
    sd_kernel<<<Nn, 256, 0, stream>>>(hbuf, asrc[l], adst[l], sbuf, dbuf, Nn);
    agg_kernel<<<Nn, 256, 0, stream>>>(hbuf, sbuf, dbuf, offsets, csr, bb[l], skipb, xouts[l], Nn);
    xin = xouts[l];
  }
}

// Round 2
// 909.243 us; speedup vs baseline: 1.6596x; 1.6596x over previous
//
#include <hip/hip_runtime.h>
#include <math.h>

// N=50000, E=800000, IN=128, H=4, C=64, HC=256
#define HEADS 4
#define CH 64
#define HC 256

typedef short bf16x8 __attribute__((ext_vector_type(8)));
typedef float f32x4 __attribute__((ext_vector_type(4)));

__device__ __forceinline__ float leaky02(float x) { return x > 0.f ? x : 0.2f * x; }
__device__ __forceinline__ float bf2f(unsigned short u) {
  unsigned int v = ((unsigned int)u) << 16;
  return __builtin_bit_cast(float, v);
}
__device__ __forceinline__ unsigned short f2bf(float f) {
  unsigned int u = __builtin_bit_cast(unsigned int, f);
  unsigned int r = u + 0x7fffu + ((u >> 16) & 1u);
  return (unsigned short)(r >> 16);
}

// ---------------------------------------------------------------------------
// Convert input x fp32 [N*128] -> bf16
// ---------------------------------------------------------------------------
__global__ __launch_bounds__(256) void convert_x(const float* __restrict__ x,
                                                 unsigned short* __restrict__ xb,
                                                 int total4) {
  int i = blockIdx.x * 256 + threadIdx.x;
  if (i >= total4) return;
  float4 v = reinterpret_cast<const float4*>(x)[i];
  ushort4 o;
  o.x = f2bf(v.x); o.y = f2bf(v.y); o.z = f2bf(v.z); o.w = f2bf(v.w);
  reinterpret_cast<ushort4*>(xb)[i] = o;
}

// ---------------------------------------------------------------------------
// Build Bt[512][K] bf16 = transpose of [W | SW] ([K][256] each, fp32)
// ---------------------------------------------------------------------------
__global__ __launch_bounds__(256) void transpose_w(const float* __restrict__ W,
                                                   const float* __restrict__ SW,
                                                   unsigned short* __restrict__ Bt, int K) {
  int idx = blockIdx.x * 256 + threadIdx.x;
  if (idx >= 512 * K) return;
  int c = idx / K, k = idx - c * K;
  float v = (c < 256) ? W[k * 256 + c] : SW[k * 256 + (c - 256)];
  Bt[idx] = f2bf(v);
}

// ---------------------------------------------------------------------------
// bf16 MFMA GEMM: out[M][512] = x[M][K] @ [W|SW][K][512]
//   cols 0..255  -> h (bf16)
//   cols 256..511-> skip (fp32, +Sb)
// 128x128 tile, BK=32, 256 thr = 4 waves (2x2), 16x16x32 MFMA, 4x4 tiles/wave.
// ---------------------------------------------------------------------------
__global__ __launch_bounds__(256) void gemm_mfma(
    const unsigned short* __restrict__ xb,   // [M][K] bf16
    const unsigned short* __restrict__ Bt,   // [512][K] bf16 (transposed weights)
    const float* __restrict__ Sb,            // [256]
    unsigned short* __restrict__ h,          // [M][256] bf16
    float* __restrict__ skip,                // [M][256] fp32
    int M, int K) {
  __shared__ unsigned short As[128 * 40];  // rows x k, stride 40 shorts (80B)
  __shared__ unsigned short Bs[128 * 40];  // cols x k

  const int t = threadIdx.x;
  const int rowBase = blockIdx.y * 128;
  const int colBase = blockIdx.x * 128;  // within [0,512)
  const int w = t >> 6, lane = t & 63;
  const int wr = (w >> 1) * 64, wc = (w & 1) * 64;
  const int lrow = lane & 15, lq = lane >> 4;

  f32x4 acc[4][4];
#pragma unroll
  for (int i = 0; i < 4; i++)
#pragma unroll
    for (int j = 0; j < 4; j++) acc[i][j] = (f32x4){0.f, 0.f, 0.f, 0.f};

  for (int k0 = 0; k0 < K; k0 += 32) {
    // Stage A and B tiles: 128 rows x 32 k each, 16B per thread per tile half
#pragma unroll
    for (int i = 0; i < 2; i++) {
      int flat = t + i * 256;            // 0..511
      int r = flat >> 2, seg = flat & 3; // row 0..127, 8-elem segment 0..3
      int gr = rowBase + r;
      if (gr >= M) gr = M - 1;
      bf16x8 av = *reinterpret_cast<const bf16x8*>(xb + (size_t)gr * K + k0 + seg * 8);
      *reinterpret_cast<bf16x8*>(&As[r * 40 + seg * 8]) = av;
      int gc = colBase + r;  // always < 512
      bf16x8 bv = *reinterpret_cast<const bf16x8*>(Bt + (size_t)gc * K + k0 + seg * 8);
      *reinterpret_cast<bf16x8*>(&Bs[r * 40 + seg * 8]) = bv;
    }
    __syncthreads();

    bf16x8 af[4], bfr[4];
#pragma unroll
    for (int i = 0; i < 4; i++) {
      af[i]  = *reinterpret_cast<const bf16x8*>(&As[(wr + i * 16 + lrow) * 40 + lq * 8]);
      bfr[i] = *reinterpret_cast<const bf16x8*>(&Bs[(wc + i * 16 + lrow) * 40 + lq * 8]);
    }
#pragma unroll
    for (int i = 0; i < 4; i++)
#pragma unroll
      for (int j = 0; j < 4; j++)
        acc[i][j] = __builtin_amdgcn_mfma_f32_16x16x32_bf16(af[i], bfr[j], acc[i][j], 0, 0, 0);
    __syncthreads();
  }

  // Epilogue: C/D layout col=lane&15, row=(lane>>4)*4+reg
#pragma unroll
  for (int i = 0; i < 4; i++) {
#pragma unroll
    for (int j = 0; j < 4; j++) {
      int gcol = colBase + wc + j * 16 + lrow;
#pragma unroll
      for (int r = 0; r < 4; r++) {
        int grow = rowBase + wr + i * 16 + lq * 4 + r;
        if (grow >= M) continue;
        float v = acc[i][j][r];
        if (gcol < 256) {
          h[(size_t)grow * 256 + gcol] = f2bf(v);
        } else {
          int c = gcol - 256;
          skip[(size_t)grow * 256 + c] = v + Sb[c];
        }
      }
    }
  }
}

// ---------------------------------------------------------------------------
// Attention logits from bf16 h
// ---------------------------------------------------------------------------
__global__ __launch_bounds__(256) void sd_kernel(
    const unsigned short* __restrict__ hb, const float* __restrict__ a_src,
    const float* __restrict__ a_dst, float* __restrict__ s, float* __restrict__ d,
    int Nn) {
  int n = blockIdx.x;
  int t = threadIdx.x;
  int head = t >> 6, lane = t & 63;
  float hv = bf2f(hb[(size_t)n * HC + t]);
  float ps = hv * a_src[t];
  float pd = hv * a_dst[t];
#pragma unroll
  for (int off = 32; off >= 1; off >>= 1) {
    ps += __shfl_down(ps, off, 64);
    pd += __shfl_down(pd, off, 64);
  }
  if (lane == 0) {
    s[n * HEADS + head] = ps;
    d[n * HEADS + head] = pd;
  }
}

// ---------------------------------------------------------------------------
// Global per-head max of s (encoded uint for atomicMax; memset-0 = -inf)
// ---------------------------------------------------------------------------
__global__ __launch_bounds__(256) void smax_kernel(const float* __restrict__ s,
                                                   unsigned int* __restrict__ smax_enc,
                                                   int total) {
  __shared__ float sm[256];
  int t = threadIdx.x;
  int i = blockIdx.x * 256 + t;
  sm[t] = (i < total) ? s[i] : -1e30f;
  __syncthreads();
  for (int off = 128; off >= 4; off >>= 1) {
    if (t < off) sm[t] = fmaxf(sm[t], sm[t + off]);
    __syncthreads();
  }
  if (t < 4) {
    unsigned int b = __builtin_bit_cast(unsigned int, sm[t]);
    unsigned int key = (b & 0x80000000u) ? ~b : (b | 0x80000000u);
    atomicMax(&smax_enc[t], key);
  }
}

// ---------------------------------------------------------------------------
// CSR build
// ---------------------------------------------------------------------------
__global__ void hist_kernel(const int* __restrict__ ei, int* __restrict__ counts, int E) {
  int e = blockIdx.x * 256 + threadIdx.x;
  if (e < E) atomicAdd(&counts[ei[E + e]], 1);
}

__global__ __launch_bounds__(1024) void scan_kernel(
    const int* __restrict__ counts, int* __restrict__ offsets,
    int* __restrict__ cursor, int n) {
  __shared__ int sdata[1024];
  __shared__ int srun;
  int tid = threadIdx.x;
  if (tid == 0) srun = 0;
  __syncthreads();
  for (int base = 0; base < n; base += 1024) {
    int i = base + tid;
    int v = (i < n) ? counts[i] : 0;
    sdata[tid] = v;
    __syncthreads();
    for (int off = 1; off < 1024; off <<= 1) {
      int tv = (tid >= off) ? sdata[tid - off] : 0;
      __syncthreads();
      sdata[tid] += tv;
      __syncthreads();
    }
    int run = srun;
    int excl = run + sdata[tid] - v;
    if (i < n) {
      offsets[i] = excl;
      cursor[i] = excl;
    }
    __syncthreads();
    if (tid == 1023) srun = run + sdata[1023];
    __syncthreads();
  }
  if (tid == 0) offsets[n] = srun;
}

__global__ void scatter_kernel(const int* __restrict__ ei, int* __restrict__ cursor,
                               int* __restrict__ csr, int E) {
  int e = blockIdx.x * 256 + threadIdx.x;
  if (e < E) {
    int dn = ei[E + e];
    int pos = atomicAdd(&cursor[dn], 1);
    csr[pos] = ei[e];
  }
}

// ---------------------------------------------------------------------------
// Single-pass aggregation (global-max softmax bound) + epilogue.
// One block per dst node, wave per head, lane = channel. h is bf16.
// ---------------------------------------------------------------------------
__global__ __launch_bounds__(256) void agg_kernel(
    const unsigned short* __restrict__ hb, const float* __restrict__ s,
    const float* __restrict__ d, const unsigned int* __restrict__ smax_enc,
    const int* __restrict__ offsets, const int* __restrict__ csr,
    const float* __restrict__ b, const float* __restrict__ skip,
    float* __restrict__ xout_f, unsigned short* __restrict__ xout_b,
    int Nn, int write_f) {
  int n = blockIdx.x;
  int head = threadIdx.x >> 6;
  int lane = threadIdx.x & 63;
  int beg = offsets[n], end = offsets[n + 1];

  float dn = d[n * HEADS + head];
  unsigned int key = smax_enc[head];
  unsigned int mb = (key & 0x80000000u) ? (key & 0x7fffffffu) : ~key;
  float m = leaky02(__builtin_bit_cast(float, mb) + dn);  // upper bound for all e of this (n,head)
  int col = head * CH + lane;

  float a0 = 0.f, a1 = 0.f, a2 = 0.f, a3 = 0.f;
  float d0 = 0.f, d1 = 0.f, d2 = 0.f, d3 = 0.f;
  for (int base = beg; base < end; base += 64) {
    int cnt = min(64, end - base);
    int sn_l = 0;
    float e_l = 0.f;
    if (lane < cnt) {
      sn_l = csr[base + lane];
      e_l = __expf(leaky02(s[sn_l * HEADS + head] + dn) - m);
    }
    int j = 0;
    for (; j + 4 <= cnt; j += 4) {
      int s0 = __shfl(sn_l, j, 64), s1 = __shfl(sn_l, j + 1, 64);
      int s2 = __shfl(sn_l, j + 2, 64), s3 = __shfl(sn_l, j + 3, 64);
      float e0 = __shfl(e_l, j, 64), e1 = __shfl(e_l, j + 1, 64);
      float e2 = __shfl(e_l, j + 2, 64), e3 = __shfl(e_l, j + 3, 64);
      float h0 = bf2f(hb[(size_t)s0 * HC + col]);
      float h1 = bf2f(hb[(size_t)s1 * HC + col]);
      float h2 = bf2f(hb[(size_t)s2 * HC + col]);
      float h3 = bf2f(hb[(size_t)s3 * HC + col]);
      d0 += e0; d1 += e1; d2 += e2; d3 += e3;
      a0 += e0 * h0; a1 += e1 * h1; a2 += e2 * h2; a3 += e3 * h3;
    }
    for (; j < cnt; j++) {
      int sn = __shfl(sn_l, j, 64);
      float ex = __shfl(e_l, j, 64);
      d0 += ex;
      a0 += ex * bf2f(hb[(size_t)sn * HC + col]);
    }
  }
  // self loop
  float e_self = __expf(leaky02(s[n * HEADS + head] + dn) - m);
  float denom = d0 + d1 + d2 + d3 + e_self;
  float acc = a0 + a1 + a2 + a3 + e_self * bf2f(hb[(size_t)n * HC + col]);

  float res = acc / (denom + 1e-16f) + b[col] + skip[(size_t)n * HC + col];
  res = res > 0.f ? res : expm1f(res);
  if (write_f) xout_f[(size_t)n * HC + col] = res;
  else xout_b[(size_t)n * HC + col] = f2bf(res);
}

// ---------------------------------------------------------------------------
extern "C" void kernel_launch(void* const* d_in, const int* in_sizes, int n_in,
                              void* d_out, int out_size, void* d_ws, size_t ws_size,
                              hipStream_t stream) {
  const float* x = (const float*)d_in[0];
  const int* ei = (const int*)d_in[1];
  const int Nn = in_sizes[0] / 128;  // 50000
  const int E = in_sizes[1] / 2;     // 800000

  const float* W[3]; const float* asrc[3]; const float* adst[3];
  const float* bb[3]; const float* SW[3]; const float* Sb[3];
  for (int l = 0; l < 3; l++) {
    W[l]    = (const float*)d_in[2 + 6 * l + 0];
    asrc[l] = (const float*)d_in[2 + 6 * l + 1];
    adst[l] = (const float*)d_in[2 + 6 * l + 2];
    bb[l]   = (const float*)d_in[2 + 6 * l + 3];
    SW[l]   = (const float*)d_in[2 + 6 * l + 4];
    Sb[l]   = (const float*)d_in[2 + 6 * l + 5];
  }

  // Workspace layout
  char* p = (char*)d_ws;
  unsigned short* hb  = (unsigned short*)p; p += (size_t)Nn * HC * 2;       // bf16 h
  unsigned short* xb  = (unsigned short*)p; p += (size_t)Nn * HC * 2;       // bf16 layer io
  unsigned short* x1b = (unsigned short*)p; p += (size_t)Nn * 128 * 2;      // bf16 input x
  unsigned short* Bt  = (unsigned short*)p; p += (size_t)512 * 256 * 2;     // bf16 weights^T
  float* skipb = (float*)p; p += (size_t)Nn * HC * 4;
  float* sbuf  = (float*)p; p += (size_t)Nn * HEADS * 4;
  float* dbuf  = (float*)p; p += (size_t)Nn * HEADS * 4;
  unsigned int* smax_enc = (unsigned int*)p; p += 4 * sizeof(unsigned int) + 48;  // pad to 16B
  int* counts  = (int*)p; p += (size_t)Nn * 4;
  int* offsets = (int*)p; p += (size_t)(Nn + 1) * 4;
  int* cursor  = (int*)p; p += (size_t)Nn * 4;
  int* csr     = (int*)p; p += (size_t)E * 4;

  // --- CSR build (dst is layer-invariant) ---
  hipMemsetAsync(counts, 0, (size_t)Nn * sizeof(int), stream);
  hist_kernel<<<(E + 255) / 256, 256, 0, stream>>>(ei, counts, E);
  scan_kernel<<<1, 1024, 0, stream>>>(counts, offsets, cursor, Nn);
  scatter_kernel<<<(E + 255) / 256, 256, 0, stream>>>(ei, cursor, csr, E);

  // --- Input conversion ---
  int t4 = Nn * 128 / 4;
  convert_x<<<(t4 + 255) / 256, 256, 0, stream>>>(x, x1b, t4);

  // --- Layers ---
  dim3 ggrid(4, (Nn + 127) / 128);
  for (int l = 0; l < 3; l++) {
    int K = (l == 0) ? 128 : 256;
    const unsigned short* xin = (l == 0) ? x1b : xb;
    transpose_w<<<(512 * K + 255) / 256, 256, 0, stream>>>(W[l], SW[l], Bt, K);
    gemm_mfma<<<ggrid, 256, 0, stream>>>(xin, Bt, Sb[l], hb, skipb, Nn, K);
    sd_kernel<<<Nn, 256, 0, stream>>>(hb, asrc[l], adst[l], sbuf, dbuf, Nn);
    hipMemsetAsync(smax_enc, 0, 4 * sizeof(unsigned int), stream);
    smax_kernel<<<(Nn * HEADS + 255) / 256, 256, 0, stream>>>(sbuf, smax_enc, Nn * HEADS);
    agg_kernel<<<Nn, 256, 0, stream>>>(hb, sbuf, dbuf, smax_enc, offsets, csr,
                                       bb[l], skipb, (float*)d_out, xb, Nn,
                                       (l == 2) ? 1 : 0);
  }
}

// Round 3
// 708.574 us; speedup vs baseline: 2.1296x; 1.2832x over previous
//
#include <hip/hip_runtime.h>
#include <math.h>

// N=50000, E=800000, IN=128, H=4, C=64, HC=256
#define HEADS 4
#define CH 64
#define HC 256

typedef short bf16x8 __attribute__((ext_vector_type(8)));
typedef float f32x4 __attribute__((ext_vector_type(4)));

__device__ __forceinline__ float leaky02(float x) { return x > 0.f ? x : 0.2f * x; }
__device__ __forceinline__ float bf2f(unsigned short u) {
  unsigned int v = ((unsigned int)u) << 16;
  return __builtin_bit_cast(float, v);
}
__device__ __forceinline__ unsigned short f2bf(float f) {
  unsigned int u = __builtin_bit_cast(unsigned int, f);
  unsigned int r = u + 0x7fffu + ((u >> 16) & 1u);
  return (unsigned short)(r >> 16);
}
__device__ __forceinline__ float decode_max(unsigned int key) {
  unsigned int mb = (key & 0x80000000u) ? (key & 0x7fffffffu) : ~key;
  return __builtin_bit_cast(float, mb);
}
__device__ __forceinline__ float4 bf4_to_f4(ushort4 u) {
  float4 r;
  r.x = bf2f(u.x); r.y = bf2f(u.y); r.z = bf2f(u.z); r.w = bf2f(u.w);
  return r;
}

// ---------------------------------------------------------------------------
// Convert input x fp32 [N*128] -> bf16
// ---------------------------------------------------------------------------
__global__ __launch_bounds__(256) void convert_x(const float* __restrict__ x,
                                                 unsigned short* __restrict__ xb,
                                                 int total4) {
  int i = blockIdx.x * 256 + threadIdx.x;
  if (i >= total4) return;
  float4 v = reinterpret_cast<const float4*>(x)[i];
  ushort4 o;
  o.x = f2bf(v.x); o.y = f2bf(v.y); o.z = f2bf(v.z); o.w = f2bf(v.w);
  reinterpret_cast<ushort4*>(xb)[i] = o;
}

// ---------------------------------------------------------------------------
// LDS-tiled transpose: Bt[512][K] bf16 = [W | SW]^T  (W/SW are [K][256] fp32)
// grid (K/64, 8), 256 threads, 64x64 tile.
// ---------------------------------------------------------------------------
__global__ __launch_bounds__(256) void transpose_w(const float* __restrict__ W,
                                                   const float* __restrict__ SW,
                                                   unsigned short* __restrict__ Bt, int K) {
  __shared__ unsigned short tile[64][72];  // row stride 144B (16B aligned)
  int k0 = blockIdx.x * 64;
  int c0 = blockIdx.y * 64;  // 0..511
  const float* __restrict__ src = (c0 < 256) ? W : SW;
  int cc = (c0 < 256) ? c0 : c0 - 256;

  int t = threadIdx.x;
  int r = t >> 2, q4 = (t & 3) * 16;
#pragma unroll
  for (int q = 0; q < 4; q++) {
    float4 v = *reinterpret_cast<const float4*>(src + (size_t)(k0 + r) * 256 + cc + q4 + q * 4);
    tile[q4 + q * 4 + 0][r] = f2bf(v.x);
    tile[q4 + q * 4 + 1][r] = f2bf(v.y);
    tile[q4 + q * 4 + 2][r] = f2bf(v.z);
    tile[q4 + q * 4 + 3][r] = f2bf(v.w);
  }
  __syncthreads();
  int c = t >> 2, kq = (t & 3) * 16;
#pragma unroll
  for (int q = 0; q < 2; q++) {
    bf16x8 v = *reinterpret_cast<const bf16x8*>(&tile[c][kq + q * 8]);
    *reinterpret_cast<bf16x8*>(Bt + (size_t)(c0 + c) * K + k0 + kq + q * 8) = v;
  }
}

// ---------------------------------------------------------------------------
// bf16 MFMA GEMM: out[M][512] = x[M][K] @ [W|SW][K][512]
// ---------------------------------------------------------------------------
__global__ __launch_bounds__(256) void gemm_mfma(
    const unsigned short* __restrict__ xb, const unsigned short* __restrict__ Bt,
    const float* __restrict__ Sb, unsigned short* __restrict__ h,
    float* __restrict__ skip, int M, int K) {
  __shared__ unsigned short As[128 * 40];
  __shared__ unsigned short Bs[128 * 40];

  const int t = threadIdx.x;
  const int rowBase = blockIdx.y * 128;
  const int colBase = blockIdx.x * 128;
  const int w = t >> 6, lane = t & 63;
  const int wr = (w >> 1) * 64, wc = (w & 1) * 64;
  const int lrow = lane & 15, lq = lane >> 4;

  f32x4 acc[4][4];
#pragma unroll
  for (int i = 0; i < 4; i++)
#pragma unroll
    for (int j = 0; j < 4; j++) acc[i][j] = (f32x4){0.f, 0.f, 0.f, 0.f};

  for (int k0 = 0; k0 < K; k0 += 32) {
#pragma unroll
    for (int i = 0; i < 2; i++) {
      int flat = t + i * 256;
      int r = flat >> 2, seg = flat & 3;
      int gr = rowBase + r;
      if (gr >= M) gr = M - 1;
      bf16x8 av = *reinterpret_cast<const bf16x8*>(xb + (size_t)gr * K + k0 + seg * 8);
      *reinterpret_cast<bf16x8*>(&As[r * 40 + seg * 8]) = av;
      int gc = colBase + r;
      bf16x8 bv = *reinterpret_cast<const bf16x8*>(Bt + (size_t)gc * K + k0 + seg * 8);
      *reinterpret_cast<bf16x8*>(&Bs[r * 40 + seg * 8]) = bv;
    }
    __syncthreads();

    bf16x8 af[4], bfr[4];
#pragma unroll
    for (int i = 0; i < 4; i++) {
      af[i]  = *reinterpret_cast<const bf16x8*>(&As[(wr + i * 16 + lrow) * 40 + lq * 8]);
      bfr[i] = *reinterpret_cast<const bf16x8*>(&Bs[(wc + i * 16 + lrow) * 40 + lq * 8]);
    }
#pragma unroll
    for (int i = 0; i < 4; i++)
#pragma unroll
      for (int j = 0; j < 4; j++)
        acc[i][j] = __builtin_amdgcn_mfma_f32_16x16x32_bf16(af[i], bfr[j], acc[i][j], 0, 0, 0);
    __syncthreads();
  }

#pragma unroll
  for (int i = 0; i < 4; i++) {
#pragma unroll
    for (int j = 0; j < 4; j++) {
      int gcol = colBase + wc + j * 16 + lrow;
#pragma unroll
      for (int r = 0; r < 4; r++) {
        int grow = rowBase + wr + i * 16 + lq * 4 + r;
        if (grow >= M) continue;
        float v = acc[i][j][r];
        if (gcol < 256) {
          h[(size_t)grow * 256 + gcol] = f2bf(v);
        } else {
          int c = gcol - 256;
          skip[(size_t)grow * 256 + c] = v + Sb[c];
        }
      }
    }
  }
}

// ---------------------------------------------------------------------------
// Attention logits: wave per node, lane covers 4 cols (ushort4).
// ---------------------------------------------------------------------------
__global__ __launch_bounds__(256) void sd_kernel(
    const unsigned short* __restrict__ hb, const float* __restrict__ a_src,
    const float* __restrict__ a_dst, float* __restrict__ s, float* __restrict__ d,
    int Nn) {
  int n = blockIdx.x * 4 + (threadIdx.x >> 6);
  if (n >= Nn) return;
  int lane = threadIdx.x & 63;
  int col = lane * 4;
  float4 h4 = bf4_to_f4(*reinterpret_cast<const ushort4*>(hb + (size_t)n * HC + col));
  float4 as4 = *reinterpret_cast<const float4*>(a_src + col);
  float4 ad4 = *reinterpret_cast<const float4*>(a_dst + col);
  float ps = h4.x * as4.x + h4.y * as4.y + h4.z * as4.z + h4.w * as4.w;
  float pd = h4.x * ad4.x + h4.y * ad4.y + h4.z * ad4.z + h4.w * ad4.w;
#pragma unroll
  for (int off = 1; off < 16; off <<= 1) {
    ps += __shfl_xor(ps, off, 64);
    pd += __shfl_xor(pd, off, 64);
  }
  if ((lane & 15) == 0) {
    int head = lane >> 4;
    s[n * HEADS + head] = ps;
    d[n * HEADS + head] = pd;
  }
}

// ---------------------------------------------------------------------------
// Global per-head max of s (encoded uint for atomicMax; memset-0 init)
// ---------------------------------------------------------------------------
__global__ __launch_bounds__(256) void smax_kernel(const float* __restrict__ s,
                                                   unsigned int* __restrict__ smax_enc,
                                                   int total) {
  __shared__ float sm[256];
  int t = threadIdx.x;
  int i = blockIdx.x * 256 + t;
  sm[t] = (i < total) ? s[i] : -1e30f;
  __syncthreads();
  for (int off = 128; off >= 4; off >>= 1) {
    if (t < off) sm[t] = fmaxf(sm[t], sm[t + off]);
    __syncthreads();
  }
  if (t < 4) {
    unsigned int b = __builtin_bit_cast(unsigned int, sm[t]);
    unsigned int key = (b & 0x80000000u) ? ~b : (b | 0x80000000u);
    atomicMax(&smax_enc[t], key);
  }
}

// ---------------------------------------------------------------------------
// CSR build (padded to multiple-of-4 segments)
// ---------------------------------------------------------------------------
__global__ void hist_kernel(const int* __restrict__ ei, int* __restrict__ counts, int E) {
  int e = blockIdx.x * 256 + threadIdx.x;
  if (e < E) atomicAdd(&counts[ei[E + e]], 1);
}

__global__ __launch_bounds__(1024) void scan_kernel(
    const int* __restrict__ counts, int* __restrict__ offsets,
    int* __restrict__ cursor, int n) {
  __shared__ int wsums[16];
  __shared__ int srun;
  int tid = threadIdx.x;
  int lane = tid & 63, wv = tid >> 6;
  if (tid == 0) srun = 0;
  __syncthreads();
  for (int base = 0; base < n; base += 1024) {
    int i = base + tid;
    int c = (i < n) ? counts[i] : 0;
    int v = (c + 3) & ~3;  // pad each segment to multiple of 4
    int incl = v;
#pragma unroll
    for (int off = 1; off < 64; off <<= 1) {
      int tv = __shfl_up(incl, off, 64);
      if (lane >= off) incl += tv;
    }
    if (lane == 63) wsums[wv] = incl;
    __syncthreads();
    if (wv == 0) {
      int wval = (lane < 16) ? wsums[lane] : 0;
      int winc = wval;
#pragma unroll
      for (int off = 1; off < 16; off <<= 1) {
        int tv = __shfl_up(winc, off, 64);
        if (lane >= off) winc += tv;
      }
      if (lane < 16) wsums[lane] = winc - wval;
    }
    __syncthreads();
    int excl = srun + wsums[wv] + incl - v;
    if (i < n) { offsets[i] = excl; cursor[i] = excl; }
    __syncthreads();
    if (tid == 1023) srun = excl + v;
    __syncthreads();
  }
  if (tid == 0) offsets[n] = srun;
}

__global__ void scatter_kernel(const int* __restrict__ ei, int* __restrict__ cursor,
                               int* __restrict__ csr, int* __restrict__ csr_dst, int E) {
  int e = blockIdx.x * 256 + threadIdx.x;
  if (e < E) {
    int dn = ei[E + e];
    int pos = atomicAdd(&cursor[dn], 1);
    csr[pos] = ei[e];
    csr_dst[pos] = dn;
  }
}

// Fill padding slots: csr=0 (valid row), csr_dst=-1 (marker -> e=0)
__global__ void pad_kernel(const int* __restrict__ counts, const int* __restrict__ offsets,
                           int* __restrict__ csr, int* __restrict__ csr_dst, int Nn) {
  int n = blockIdx.x * 256 + threadIdx.x;
  if (n >= Nn) return;
  int e0 = offsets[n] + counts[n];
  int e1 = offsets[n + 1];
  for (int i = e0; i < e1; i++) { csr[i] = 0; csr_dst[i] = -1; }
}

// ---------------------------------------------------------------------------
// Per-slot softmax numerators, 4 head planes: eexp[h*eps + i]
// ---------------------------------------------------------------------------
__global__ __launch_bounds__(256) void edge_e_kernel(
    const int* __restrict__ csr, const int* __restrict__ csr_dst,
    const float* __restrict__ s, const float* __restrict__ d,
    const unsigned int* __restrict__ smax_enc, float* __restrict__ eexp,
    int eps, const int* __restrict__ etot_ptr) {
  int i = blockIdx.x * 256 + threadIdx.x;
  if (i >= etot_ptr[0]) return;
  int dn = csr_dst[i];
  if (dn < 0) {
    eexp[i] = 0.f; eexp[eps + i] = 0.f; eexp[2 * eps + i] = 0.f; eexp[3 * eps + i] = 0.f;
    return;
  }
  int sn = csr[i];
  float4 s4 = *reinterpret_cast<const float4*>(s + sn * 4);
  float4 d4 = *reinterpret_cast<const float4*>(d + dn * 4);
  eexp[0 * eps + i] = __expf(leaky02(s4.x + d4.x) - leaky02(decode_max(smax_enc[0]) + d4.x));
  eexp[1 * eps + i] = __expf(leaky02(s4.y + d4.y) - leaky02(decode_max(smax_enc[1]) + d4.y));
  eexp[2 * eps + i] = __expf(leaky02(s4.z + d4.z) - leaky02(decode_max(smax_enc[2]) + d4.z));
  eexp[3 * eps + i] = __expf(leaky02(s4.w + d4.w) - leaky02(decode_max(smax_enc[3]) + d4.w));
}

// ---------------------------------------------------------------------------
// Aggregation v2: one wave per node, lane owns cols 4l..4l+3 (all heads).
// ---------------------------------------------------------------------------
__global__ __launch_bounds__(256) void agg_kernel(
    const unsigned short* __restrict__ hb, const float* __restrict__ s,
    const float* __restrict__ d, const unsigned int* __restrict__ smax_enc,
    const int* __restrict__ offsets, const int* __restrict__ csr,
    const float* __restrict__ eexp, int eps,
    const float* __restrict__ b, const float* __restrict__ skip,
    float* __restrict__ xout_f, unsigned short* __restrict__ xout_b,
    int Nn, int write_f) {
  int n = blockIdx.x * 4 + (threadIdx.x >> 6);
  if (n >= Nn) return;
  int lane = threadIdx.x & 63;
  int head = lane >> 4;
  int col = lane * 4;

  int beg = offsets[n], end = offsets[n + 1];
  const float* __restrict__ eh = eexp + head * eps;

  float4 asum = make_float4(0.f, 0.f, 0.f, 0.f);
  float dsum = 0.f;

  for (int i = beg; i < end; i += 4) {
    int4 sn = *reinterpret_cast<const int4*>(csr + i);
    float4 ev = *reinterpret_cast<const float4*>(eh + i);
    ushort4 u0 = *reinterpret_cast<const ushort4*>(hb + sn.x * HC + col);
    ushort4 u1 = *reinterpret_cast<const ushort4*>(hb + sn.y * HC + col);
    ushort4 u2 = *reinterpret_cast<const ushort4*>(hb + sn.z * HC + col);
    ushort4 u3 = *reinterpret_cast<const ushort4*>(hb + sn.w * HC + col);
    float4 f0 = bf4_to_f4(u0), f1 = bf4_to_f4(u1), f2 = bf4_to_f4(u2), f3 = bf4_to_f4(u3);
    asum.x += ev.x * f0.x + ev.y * f1.x + ev.z * f2.x + ev.w * f3.x;
    asum.y += ev.x * f0.y + ev.y * f1.y + ev.z * f2.y + ev.w * f3.y;
    asum.z += ev.x * f0.z + ev.y * f1.z + ev.z * f2.z + ev.w * f3.z;
    asum.w += ev.x * f0.w + ev.y * f1.w + ev.z * f2.w + ev.w * f3.w;
    dsum += ev.x + ev.y + ev.z + ev.w;
  }

  // self loop
  float sv = s[n * 4 + head], dv = d[n * 4 + head];
  float m = leaky02(decode_max(smax_enc[head]) + dv);
  float es = __expf(leaky02(sv + dv) - m);
  float4 hs = bf4_to_f4(*reinterpret_cast<const ushort4*>(hb + n * HC + col));
  asum.x += es * hs.x; asum.y += es * hs.y; asum.z += es * hs.z; asum.w += es * hs.w;
  dsum += es;

  float inv = 1.f / (dsum + 1e-16f);
  float4 sk = *reinterpret_cast<const float4*>(skip + (size_t)n * HC + col);
  float4 b4 = *reinterpret_cast<const float4*>(b + col);
  float4 res;
  res.x = asum.x * inv + b4.x + sk.x;
  res.y = asum.y * inv + b4.y + sk.y;
  res.z = asum.z * inv + b4.z + sk.z;
  res.w = asum.w * inv + b4.w + sk.w;
  res.x = res.x > 0.f ? res.x : expm1f(res.x);
  res.y = res.y > 0.f ? res.y : expm1f(res.y);
  res.z = res.z > 0.f ? res.z : expm1f(res.z);
  res.w = res.w > 0.f ? res.w : expm1f(res.w);
  if (write_f) {
    *reinterpret_cast<float4*>(xout_f + (size_t)n * HC + col) = res;
  } else {
    ushort4 o;
    o.x = f2bf(res.x); o.y = f2bf(res.y); o.z = f2bf(res.z); o.w = f2bf(res.w);
    *reinterpret_cast<ushort4*>(xout_b + (size_t)n * HC + col) = o;
  }
}

// ---------------------------------------------------------------------------
extern "C" void kernel_launch(void* const* d_in, const int* in_sizes, int n_in,
                              void* d_out, int out_size, void* d_ws, size_t ws_size,
                              hipStream_t stream) {
  const float* x = (const float*)d_in[0];
  const int* ei = (const int*)d_in[1];
  const int Nn = in_sizes[0] / 128;  // 50000
  const int E = in_sizes[1] / 2;     // 800000
  const int EPS = E + 3 * Nn;        // max padded CSR size (950000, %4==0)

  const float* W[3]; const float* asrc[3]; const float* adst[3];
  const float* bb[3]; const float* SW[3]; const float* Sb[3];
  for (int l = 0; l < 3; l++) {
    W[l]    = (const float*)d_in[2 + 6 * l + 0];
    asrc[l] = (const float*)d_in[2 + 6 * l + 1];
    adst[l] = (const float*)d_in[2 + 6 * l + 2];
    bb[l]   = (const float*)d_in[2 + 6 * l + 3];
    SW[l]   = (const float*)d_in[2 + 6 * l + 4];
    Sb[l]   = (const float*)d_in[2 + 6 * l + 5];
  }

  // Workspace layout (all chunks 16B-aligned)
  char* p = (char*)d_ws;
  unsigned short* hb  = (unsigned short*)p; p += (size_t)Nn * HC * 2;
  unsigned short* xb  = (unsigned short*)p; p += (size_t)Nn * HC * 2;
  unsigned short* x1b = (unsigned short*)p; p += (size_t)Nn * 128 * 2;
  unsigned short* Bt  = (unsigned short*)p; p += (size_t)512 * 256 * 2;
  float* skipb = (float*)p; p += (size_t)Nn * HC * 4;
  float* sbuf  = (float*)p; p += (size_t)Nn * HEADS * 4;
  float* dbuf  = (float*)p; p += (size_t)Nn * HEADS * 4;
  float* eexp  = (float*)p; p += (size_t)4 * EPS * 4;
  unsigned int* smax_enc = (unsigned int*)p; p += 64;
  int* counts  = (int*)p; p += (size_t)Nn * 4;
  int* offsets = (int*)p; p += ((size_t)(Nn + 1) * 4 + 15) & ~(size_t)15;
  int* cursor  = (int*)p; p += (size_t)Nn * 4;
  int* csr     = (int*)p; p += (size_t)EPS * 4;
  int* csr_dst = (int*)p; p += (size_t)EPS * 4;

  // --- CSR build (once; dst is layer-invariant) ---
  hipMemsetAsync(counts, 0, (size_t)Nn * sizeof(int), stream);
  hist_kernel<<<(E + 255) / 256, 256, 0, stream>>>(ei, counts, E);
  scan_kernel<<<1, 1024, 0, stream>>>(counts, offsets, cursor, Nn);
  scatter_kernel<<<(E + 255) / 256, 256, 0, stream>>>(ei, cursor, csr, csr_dst, E);
  pad_kernel<<<(Nn + 255) / 256, 256, 0, stream>>>(counts, offsets, csr, csr_dst, Nn);

  // --- Input conversion ---
  int t4 = Nn * 128 / 4;
  convert_x<<<(t4 + 255) / 256, 256, 0, stream>>>(x, x1b, t4);

  // --- Layers ---
  dim3 ggrid(4, (Nn + 127) / 128);
  int nblk4 = (Nn + 3) / 4;
  for (int l = 0; l < 3; l++) {
    int K = (l == 0) ? 128 : 256;
    const unsigned short* xin = (l == 0) ? x1b : xb;
    transpose_w<<<dim3(K / 64, 8), 256, 0, stream>>>(W[l], SW[l], Bt, K);
    gemm_mfma<<<ggrid, 256, 0, stream>>>(xin, Bt, Sb[l], hb, skipb, Nn, K);
    sd_kernel<<<nblk4, 256, 0, stream>>>(hb, asrc[l], adst[l], sbuf, dbuf, Nn);
    hipMemsetAsync(smax_enc, 0, 4 * sizeof(unsigned int), stream);
    smax_kernel<<<(Nn * HEADS + 255) / 256, 256, 0, stream>>>(sbuf, smax_enc, Nn * HEADS);
    edge_e_kernel<<<(EPS + 255) / 256, 256, 0, stream>>>(csr, csr_dst, sbuf, dbuf,
                                                         smax_enc, eexp, EPS, offsets + Nn);
    agg_kernel<<<nblk4, 256, 0, stream>>>(hb, sbuf, dbuf, smax_enc, offsets, csr,
                                          eexp, EPS, bb[l], skipb, (float*)d_out, xb,
                                          Nn, (l == 2) ? 1 : 0);
  }
}